// Round 5
// baseline (177.686 us; speedup 1.0000x reference)
//
#include <hip/hip_runtime.h>
#include <math.h>

#define DIM 64
#define SEQ 784
#define BATCH 256

// ---------- cross-lane helpers (wave64 full reduction via DPP) ----------
template <int CTRL>
__device__ __forceinline__ float dpp_add_step(float s) {
    int v = __builtin_amdgcn_update_dpp(0, __float_as_int(s), CTRL, 0xF, 0xF, false);
    return s + __int_as_float(v);
}

// Sum across all 64 lanes; result broadcast (uniform, via readlane 63).
__device__ __forceinline__ float wave_allsum(float x) {
    x = dpp_add_step<0xB1>(x);   // quad_perm [1,0,3,2]  (xor 1)
    x = dpp_add_step<0x4E>(x);   // quad_perm [2,3,0,1]  (xor 2)
    x = dpp_add_step<0x141>(x);  // row_half_mirror      (pairs across quads)
    x = dpp_add_step<0x140>(x);  // row_mirror           (pairs across 8-groups)
    x = dpp_add_step<0x142>(x);  // row_bcast15          (16 -> 32)
    x = dpp_add_step<0x143>(x);  // row_bcast31          (32 -> 64, lane63 = total)
    return __int_as_float(__builtin_amdgcn_readlane(__float_as_int(x), 63));
}

__device__ __forceinline__ float gelu_exact(float v) {
    return 0.5f * v * (1.0f + erff(v * 0.70710678118654752440f));
}

// ---------- manual VMEM: compiler emits NO waitcnt for asm loads ----------
__device__ __forceinline__ float gload_f32(const float* p) {
    float r;
    asm volatile("global_load_dword %0, %1, off" : "=v"(r) : "v"(p));
    return r;
}
#define VMWAIT(N)                                                   \
    do {                                                            \
        asm volatile("s_waitcnt vmcnt(" #N ")" ::: "memory");       \
        __builtin_amdgcn_sched_barrier(0);                          \
    } while (0)

// Zero-instruction cross-lane LDS ordering for a single wave: same-wave DS
// ops complete in order in HW; this only stops the COMPILER from reordering
// memory ops across the point.
#define WAVE_FENCE()                                                \
    do {                                                            \
        __builtin_amdgcn_wave_barrier();                            \
        asm volatile("" ::: "memory");                              \
    } while (0)

// ---------- prepass: k[b,s,:] and alpha[b,s] for all rows ----------
// 4096 blocks x 64 thr (one wave per block; all resident). No barriers:
// hbuf is wave-private, double-buffered; WAVE_FENCE gives compile-time
// write->read ordering, HW DS in-order does the rest. No per-row vmcnt(0)
// store drain (that was the __syncthreads cost).
__global__ __launch_bounds__(64) void prepass_kernel(
    const float* __restrict__ x, const float* __restrict__ W_in,
    const float* __restrict__ pos_emb, const float* __restrict__ Wk,
    const float* __restrict__ Wb, const float* __restrict__ bbp,
    float* __restrict__ k_ws, float* __restrict__ alpha_ws)
{
    const int lane = threadIdx.x;
    const int gw   = blockIdx.x;              // 0..4095
    const int b    = gw >> 4;                 // /16
    const int s0   = (gw & 15) * 49;

    float4 wkr[16];
    const float4* wk4 = (const float4*)(Wk + lane * 64);  // lane owns Wk row `lane`
#pragma unroll
    for (int i = 0; i < 16; ++i) wkr[i] = wk4[i];
    const float win = W_in[lane];
    const float wb  = Wb[lane];
    const float bb  = bbp[0];

    // batch the 49 scalar x loads into one lane-spread load
    const float xv = (lane < 49) ? x[b * SEQ + s0 + lane] : 0.f;

    __shared__ __align__(16) float hbuf[2][64];

    for (int r = 0; r < 49; ++r) {
        const int s = s0 + r;
        const float xs = __shfl(xv, r);
        const float pe = pos_emb[s * 64 + lane];
        const float h  = gelu_exact(fmaf(xs, win, pe));
        const float bdot = wave_allsum(h * wb);
        float* hb = hbuf[r & 1];
        hb[lane] = h;
        WAVE_FENCE();                  // write visible (compile-time order)
        const float4* h4 = (const float4*)hb;
        float kd = 0.f;
#pragma unroll
        for (int i = 0; i < 16; ++i) {
            float4 hv = h4[i];
            kd = fmaf(hv.x, wkr[i].x, kd);
            kd = fmaf(hv.y, wkr[i].y, kd);
            kd = fmaf(hv.z, wkr[i].z, kd);
            kd = fmaf(hv.w, wkr[i].w, kd);
        }
        float lam = wave_allsum(kd * kd);
        lam = fmaxf(lam, 1e-6f);
        const float beta = 1.0f / (1.0f + expf(-(bdot + bb)));
        const float al   = -expm1f(-beta * lam) / (lam + 1e-6f);
        const int row = b * SEQ + s;
        k_ws[row * 64 + lane] = kd;
        if (lane == 0) alpha_ws[row] = al;
    }
}

// ---------- shared epilogue (fused fallback only) ----------
__device__ __forceinline__ void epilogue(
    int b, int lane, float w, float* sh,
    const float* __restrict__ Wv, const float* __restrict__ ln_g,
    const float* __restrict__ ln_b, const float* __restrict__ Wc,
    const float* __restrict__ bc, float* __restrict__ out)
{
    __syncthreads();
    sh[lane] = w;
    __syncthreads();
    float last = 0.f;
    const float4* wv4 = (const float4*)(Wv + lane * 64);
    const float4* w4  = (const float4*)sh;
#pragma unroll
    for (int i = 0; i < 16; ++i) {
        float4 hv = w4[i], vv = wv4[i];
        last = fmaf(hv.x, vv.x, last);
        last = fmaf(hv.y, vv.y, last);
        last = fmaf(hv.z, vv.z, last);
        last = fmaf(hv.w, vv.w, last);
    }
    const float mu  = wave_allsum(last) * 0.015625f;
    const float dd  = last - mu;
    const float var = wave_allsum(dd * dd) * 0.015625f;
    const float ln  = dd / sqrtf(var + 1e-5f) * ln_g[lane] + ln_b[lane];
    __syncthreads();
    sh[lane] = ln;
    __syncthreads();
    if (lane < 10) {
        float acc = bc[lane];
        const float* wc = Wc + lane * 64;
#pragma unroll
        for (int j = 0; j < 64; ++j) acc = fmaf(wc[j], sh[j], acc);
        out[b * 10 + lane] = acc;
    }
}

// ---------- backward scan, a-sequence only: one wave per batch ----------
// Pair-Gram regroup (exact; validated R1/R2/R4). Staging is register-FREE
// across compute: 16 asm loads -> regs die at the next ds_write; CMP reads
// K from LDS. Per iter: VMWAIT(0) [drains the 16 loads of chunk c+1, the
// only outstanding VMEM]; WR(c+1); SLOAD(c+2); CMP(c) [~650 cyc, covers
// c+2's latency]. asm-volatile program order makes VMWAIT(0) exact; the
// memory clobber doubles as the LDS WAR fence for buffer reuse.
__global__ __launch_bounds__(64) void scan_a_kernel(
    const float* __restrict__ x, const float* __restrict__ pos_emb,
    const float* __restrict__ W_in, const float* __restrict__ Wq,
    const float* __restrict__ k_ws, float* ab /* alpha in, a out */)
{
    const int lane = threadIdx.x;
    const int b    = blockIdx.x;
    __shared__ __align__(16) float kbuf[2][16][64];   // 8 KB ring
    __shared__ __align__(16) float al_lds[SEQ];       // alpha, preloaded
    __shared__ __align__(16) float a_lds[SEQ];        // a output park
    __shared__ __align__(16) float sh[64];

    const float* kb  = k_ws + (size_t)b * SEQ * 64;
    float*       abp = ab + b * SEQ;

    // preload all alpha into LDS (one-time)
#pragma unroll
    for (int j = 0; j < 13; ++j) {
        const int idx = j * 64 + lane;
        if (idx < SEQ) al_lds[idx] = abp[idx];
    }

    // u init: q at last position
    {
        const float h = gelu_exact(fmaf(x[b * SEQ + 783], W_in[lane], pos_emb[783 * 64 + lane]));
        sh[lane] = h;
    }
    __syncthreads();
    float u = 0.f;
    {
        const float4* wq4 = (const float4*)(Wq + lane * 64);
        const float4* h4  = (const float4*)sh;
#pragma unroll
        for (int i = 0; i < 16; ++i) {
            float4 hv = h4[i], qv = wq4[i];
            u = fmaf(hv.x, qv.x, u);
            u = fmaf(hv.y, qv.y, u);
            u = fmaf(hv.z, qv.z, u);
            u = fmaf(hv.w, qv.w, u);
        }
    }

    float kst[16];   // staging regs: live only SLOAD -> next WR

#define SLOAD(c)                                               \
    do {                                                       \
        const int tb_ = 783 - (c) * 16;                        \
        _Pragma("unroll")                                      \
        for (int i = 0; i < 16; ++i)                           \
            kst[i] = gload_f32(&kb[(tb_ - i) * 64 + lane]);    \
    } while (0)

#define WR(bufidx)                                             \
    do {                                                       \
        _Pragma("unroll")                                      \
        for (int i = 0; i < 16; ++i)                           \
            kbuf[bufidx][i][lane] = kst[i];                    \
    } while (0)

#define CMP(bufidx, c)                                         \
    do {                                                       \
        const int tb_ = 783 - (c) * 16;                        \
        float K[16], A[16];                                    \
        _Pragma("unroll")                                      \
        for (int i = 0; i < 16; ++i) {                         \
            K[i] = kbuf[bufidx][i][lane];                      \
            A[i] = al_lds[tb_ - i];                            \
        }                                                      \
        float aout[16];                                        \
        _Pragma("unroll")                                      \
        for (int g = 0; g < 8; ++g) {                          \
            const int i0 = 2 * g, i1 = 2 * g + 1;              \
            const float d0  = wave_allsum(u * K[i0]);          \
            const float e1  = wave_allsum(u * K[i1]);          \
            const float g01 = wave_allsum(K[i0] * K[i1]);      \
            const float a0  = A[i0] * d0;                      \
            const float d1  = fmaf(-a0, g01, e1);              \
            const float a1  = A[i1] * d1;                      \
            u = fmaf(-a0, K[i0], u);                           \
            u = fmaf(-a1, K[i1], u);                           \
            aout[i0] = a0; aout[i1] = a1;                      \
        }                                                      \
        if (lane == 0) {                                       \
            _Pragma("unroll")                                  \
            for (int i = 0; i < 16; ++i)                       \
                a_lds[tb_ - i] = aout[i];                      \
        }                                                      \
    } while (0)

    // Drain all compiler-generated prologue VMEM so counts start at 0.
    VMWAIT(0);
    SLOAD(0);
    VMWAIT(0);
    WR(0);
    SLOAD(1);
#pragma unroll 1
    for (int c = 0; c < 47; ++c) {
        VMWAIT(0);                 // chunk c+1 landed
        WR((c + 1) & 1);
        SLOAD(c + 2);              // in flight across CMP(c)
        CMP(c & 1, c);
    }
    VMWAIT(0);
    WR(0);                         // chunk 48 -> buf 0
    CMP(1, 47);
    CMP(0, 48);
#undef SLOAD
#undef WR
#undef CMP

    // flush a-sequence to global (overwrites alpha_ws in place)
    asm volatile("s_waitcnt lgkmcnt(0)" ::: "memory");
#pragma unroll
    for (int j = 0; j < 13; ++j) {
        const int idx = j * 64 + lane;
        if (idx < SEQ) abp[idx] = a_lds[idx];
    }
}

// ---------- w accumulation + epilogue at higher occupancy ----------
// grid: 256 blocks x 512 thr (8 waves). Block b: w = sum_t a_t * h_t,
// 98 steps per wave, block-reduced; wave 0 runs the epilogue.
__global__ __launch_bounds__(512) void wsum_kernel(
    const float* __restrict__ x, const float* __restrict__ W_in,
    const float* __restrict__ pos_emb, const float* __restrict__ a_ws,
    const float* __restrict__ Wv, const float* __restrict__ ln_g,
    const float* __restrict__ ln_b, const float* __restrict__ Wc,
    const float* __restrict__ bc, float* __restrict__ out)
{
    const int lane = threadIdx.x & 63;
    const int wv   = threadIdx.x >> 6;        // 0..7
    const int b    = blockIdx.x;
    const float win = W_in[lane];
    const float* ap = a_ws + b * SEQ;
    const float* xp = x + b * SEQ;

    float w = 0.f;
    const int t0 = wv * 98;
#pragma unroll 2
    for (int i = 0; i < 98; ++i) {
        const int t = t0 + i;
        const float h = gelu_exact(fmaf(xp[t], win, pos_emb[t * 64 + lane]));
        w = fmaf(ap[t], h, w);
    }

    __shared__ __align__(16) float swr[8][64];
    __shared__ __align__(16) float sh[64];
    swr[wv][lane] = w;
    __syncthreads();
    if (wv != 0) return;

    w = swr[0][lane] + swr[1][lane] + swr[2][lane] + swr[3][lane]
      + swr[4][lane] + swr[5][lane] + swr[6][lane] + swr[7][lane];
    sh[lane] = w;
    asm volatile("s_waitcnt lgkmcnt(0)" ::: "memory");
    float last = 0.f;
    const float4* wv4 = (const float4*)(Wv + lane * 64);
    const float4* w4  = (const float4*)sh;
#pragma unroll
    for (int i = 0; i < 16; ++i) {
        float4 hv = w4[i], vv = wv4[i];
        last = fmaf(hv.x, vv.x, last);
        last = fmaf(hv.y, vv.y, last);
        last = fmaf(hv.z, vv.z, last);
        last = fmaf(hv.w, vv.w, last);
    }
    const float mu  = wave_allsum(last) * 0.015625f;
    const float dd  = last - mu;
    const float var = wave_allsum(dd * dd) * 0.015625f;
    const float ln  = dd / sqrtf(var + 1e-5f) * ln_g[lane] + ln_b[lane];
    asm volatile("s_waitcnt lgkmcnt(0)" ::: "memory");
    sh[lane] = ln;
    asm volatile("s_waitcnt lgkmcnt(0)" ::: "memory");
    if (lane < 10) {
        float acc = bc[lane];
        const float* wc = Wc + lane * 64;
#pragma unroll
        for (int j = 0; j < 64; ++j) acc = fmaf(wc[j], sh[j], acc);
        out[b * 10 + lane] = acc;
    }
}

// ---------- fused fallback (no workspace needed) ----------
__global__ __launch_bounds__(64) void fused_kernel(
    const float* __restrict__ x, const float* __restrict__ W_in,
    const float* __restrict__ pos_emb, const float* __restrict__ Wq,
    const float* __restrict__ Wk, const float* __restrict__ Wv,
    const float* __restrict__ Wb, const float* __restrict__ bbp,
    const float* __restrict__ ln_g, const float* __restrict__ ln_b,
    const float* __restrict__ Wc, const float* __restrict__ bc,
    float* __restrict__ out)
{
    const int lane = threadIdx.x;
    const int b    = blockIdx.x;
    __shared__ __align__(16) float sh[64];
    const float win = W_in[lane];
    const float wb  = Wb[lane];
    const float bb  = bbp[0];

    float4 wkr[16];
    const float4* wk4 = (const float4*)(Wk + lane * 64);
#pragma unroll
    for (int i = 0; i < 16; ++i) wkr[i] = wk4[i];

    float u;
    {
        const float h = gelu_exact(fmaf(x[b * SEQ + 783], win, pos_emb[783 * 64 + lane]));
        sh[lane] = h;
        __syncthreads();
        u = 0.f;
        const float4* wq4 = (const float4*)(Wq + lane * 64);
        const float4* h4  = (const float4*)sh;
#pragma unroll
        for (int i = 0; i < 16; ++i) {
            float4 hv = h4[i], qv = wq4[i];
            u = fmaf(hv.x, qv.x, u);
            u = fmaf(hv.y, qv.y, u);
            u = fmaf(hv.z, qv.z, u);
            u = fmaf(hv.w, qv.w, u);
        }
    }
    float w = 0.f;
    for (int t = 783; t >= 0; --t) {
        const float h = gelu_exact(fmaf(x[b * SEQ + t], win, pos_emb[t * 64 + lane]));
        const float bdot = wave_allsum(h * wb);
        __syncthreads();
        sh[lane] = h;
        __syncthreads();
        float kd = 0.f;
        const float4* h4 = (const float4*)sh;
#pragma unroll
        for (int i = 0; i < 16; ++i) {
            float4 hv = h4[i];
            kd = fmaf(hv.x, wkr[i].x, kd);
            kd = fmaf(hv.y, wkr[i].y, kd);
            kd = fmaf(hv.z, wkr[i].z, kd);
            kd = fmaf(hv.w, wkr[i].w, kd);
        }
        float lam = wave_allsum(kd * kd);
        lam = fmaxf(lam, 1e-6f);
        const float beta = 1.0f / (1.0f + expf(-(bdot + bb)));
        const float al   = -expm1f(-beta * lam) / (lam + 1e-6f);
        const float dot  = wave_allsum(u * kd);
        const float a    = al * dot;
        u = fmaf(-a, kd, u);
        w = fmaf(a, h, w);
    }
    epilogue(b, lane, w, sh, Wv, ln_g, ln_b, Wc, bc, out);
}

extern "C" void kernel_launch(void* const* d_in, const int* in_sizes, int n_in,
                              void* d_out, int out_size, void* d_ws, size_t ws_size,
                              hipStream_t stream)
{
    const float* x       = (const float*)d_in[0];
    const float* W_in    = (const float*)d_in[1];
    const float* pos_emb = (const float*)d_in[2];
    const float* Wq      = (const float*)d_in[3];
    const float* Wk      = (const float*)d_in[4];
    const float* Wv      = (const float*)d_in[5];
    const float* Wb      = (const float*)d_in[6];
    const float* bb      = (const float*)d_in[7];
    const float* ln_g    = (const float*)d_in[8];
    const float* ln_b    = (const float*)d_in[9];
    const float* Wc      = (const float*)d_in[10];
    const float* bc      = (const float*)d_in[11];
    float* out = (float*)d_out;

    const size_t k_elems = (size_t)BATCH * SEQ * 64;
    const size_t need = k_elems * sizeof(float) + (size_t)BATCH * SEQ * sizeof(float);

    if (ws_size >= need) {
        float* k_ws     = (float*)d_ws;
        float* alpha_ws = k_ws + k_elems;
        prepass_kernel<<<4096, 64, 0, stream>>>(x, W_in, pos_emb, Wk, Wb, bb, k_ws, alpha_ws);
        scan_a_kernel<<<BATCH, 64, 0, stream>>>(x, pos_emb, W_in, Wq, k_ws, alpha_ws);
        wsum_kernel<<<BATCH, 512, 0, stream>>>(x, W_in, pos_emb, alpha_ws, Wv, ln_g, ln_b,
                                               Wc, bc, out);
    } else {
        fused_kernel<<<BATCH, 64, 0, stream>>>(x, W_in, pos_emb, Wq, Wk, Wv, Wb, bb,
                                               ln_g, ln_b, Wc, bc, out);
    }
}

// Round 6
// 171.280 us; speedup vs baseline: 1.0374x; 1.0374x over previous
//
#include <hip/hip_runtime.h>
#include <math.h>

#define DIM 64
#define SEQ 784
#define BATCH 256

// ---------- cross-lane helpers (wave64 reduction via DPP) ----------
template <int CTRL>
__device__ __forceinline__ float dpp_add_step(float s) {
    int v = __builtin_amdgcn_update_dpp(0, __float_as_int(s), CTRL, 0xF, 0xF, false);
    return s + __int_as_float(v);
}

// Sum across all 64 lanes; result broadcast (uniform, via readlane 63).
__device__ __forceinline__ float wave_allsum(float x) {
    x = dpp_add_step<0xB1>(x);   // quad_perm [1,0,3,2]  (xor 1)
    x = dpp_add_step<0x4E>(x);   // quad_perm [2,3,0,1]  (xor 2)
    x = dpp_add_step<0x141>(x);  // row_half_mirror      (pairs across quads)
    x = dpp_add_step<0x140>(x);  // row_mirror           (pairs across 8-groups)
    x = dpp_add_step<0x142>(x);  // row_bcast15          (16 -> 32)
    x = dpp_add_step<0x143>(x);  // row_bcast31          (32 -> 64, lane63 = total)
    return __int_as_float(__builtin_amdgcn_readlane(__float_as_int(x), 63));
}

// 16-lane row allsum: with data replicated 4x across the four rows, every
// lane ends with the FULL sum (uniform) -- 4 DPP steps, NO readlane, no
// SGPR hop. This is the validated prefix of wave_allsum.
__device__ __forceinline__ float row16_allsum(float x) {
    x = dpp_add_step<0xB1>(x);   // xor 1
    x = dpp_add_step<0x4E>(x);   // xor 2
    x = dpp_add_step<0x141>(x);  // row_half_mirror
    x = dpp_add_step<0x140>(x);  // row_mirror
    return x;
}

__device__ __forceinline__ float dot4(float4 a, float4 b) {
    return fmaf(a.w, b.w, fmaf(a.z, b.z, fmaf(a.y, b.y, a.x * b.x)));
}

__device__ __forceinline__ float gelu_exact(float v) {
    return 0.5f * v * (1.0f + erff(v * 0.70710678118654752440f));
}

// ---------- manual VMEM: compiler emits NO waitcnt for asm loads ----------
__device__ __forceinline__ float gload_f32(const float* p) {
    float r;
    asm volatile("global_load_dword %0, %1, off" : "=v"(r) : "v"(p));
    return r;
}
#define VMWAIT(N)                                                   \
    do {                                                            \
        asm volatile("s_waitcnt vmcnt(" #N ")" ::: "memory");       \
        __builtin_amdgcn_sched_barrier(0);                          \
    } while (0)

// Zero-instruction cross-lane LDS ordering for a single wave.
#define WAVE_FENCE()                                                \
    do {                                                            \
        __builtin_amdgcn_wave_barrier();                            \
        asm volatile("" ::: "memory");                              \
    } while (0)

// ---------- prepass: k[b,s,:] and alpha[b,s] for all rows ----------
// (unchanged from R5 -- validated absmax 0.0)
__global__ __launch_bounds__(64) void prepass_kernel(
    const float* __restrict__ x, const float* __restrict__ W_in,
    const float* __restrict__ pos_emb, const float* __restrict__ Wk,
    const float* __restrict__ Wb, const float* __restrict__ bbp,
    float* __restrict__ k_ws, float* __restrict__ alpha_ws)
{
    const int lane = threadIdx.x;
    const int gw   = blockIdx.x;              // 0..4095
    const int b    = gw >> 4;                 // /16
    const int s0   = (gw & 15) * 49;

    float4 wkr[16];
    const float4* wk4 = (const float4*)(Wk + lane * 64);
#pragma unroll
    for (int i = 0; i < 16; ++i) wkr[i] = wk4[i];
    const float win = W_in[lane];
    const float wb  = Wb[lane];
    const float bb  = bbp[0];

    const float xv = (lane < 49) ? x[b * SEQ + s0 + lane] : 0.f;

    __shared__ __align__(16) float hbuf[2][64];

    for (int r = 0; r < 49; ++r) {
        const int s = s0 + r;
        const float xs = __shfl(xv, r);
        const float pe = pos_emb[s * 64 + lane];
        const float h  = gelu_exact(fmaf(xs, win, pe));
        const float bdot = wave_allsum(h * wb);
        float* hb = hbuf[r & 1];
        hb[lane] = h;
        WAVE_FENCE();
        const float4* h4 = (const float4*)hb;
        float kd = 0.f;
#pragma unroll
        for (int i = 0; i < 16; ++i) {
            float4 hv = h4[i];
            kd = fmaf(hv.x, wkr[i].x, kd);
            kd = fmaf(hv.y, wkr[i].y, kd);
            kd = fmaf(hv.z, wkr[i].z, kd);
            kd = fmaf(hv.w, wkr[i].w, kd);
        }
        float lam = wave_allsum(kd * kd);
        lam = fmaxf(lam, 1e-6f);
        const float beta = 1.0f / (1.0f + expf(-(bdot + bb)));
        const float al   = -expm1f(-beta * lam) / (lam + 1e-6f);
        const int row = b * SEQ + s;
        k_ws[row * 64 + lane] = kd;
        if (lane == 0) alpha_ws[row] = al;
    }
}

// ---------- shared epilogue (fused fallback only) ----------
__device__ __forceinline__ void epilogue(
    int b, int lane, float w, float* sh,
    const float* __restrict__ Wv, const float* __restrict__ ln_g,
    const float* __restrict__ ln_b, const float* __restrict__ Wc,
    const float* __restrict__ bc, float* __restrict__ out)
{
    __syncthreads();
    sh[lane] = w;
    __syncthreads();
    float last = 0.f;
    const float4* wv4 = (const float4*)(Wv + lane * 64);
    const float4* w4  = (const float4*)sh;
#pragma unroll
    for (int i = 0; i < 16; ++i) {
        float4 hv = w4[i], vv = wv4[i];
        last = fmaf(hv.x, vv.x, last);
        last = fmaf(hv.y, vv.y, last);
        last = fmaf(hv.z, vv.z, last);
        last = fmaf(hv.w, vv.w, last);
    }
    const float mu  = wave_allsum(last) * 0.015625f;
    const float dd  = last - mu;
    const float var = wave_allsum(dd * dd) * 0.015625f;
    const float ln  = dd / sqrtf(var + 1e-5f) * ln_g[lane] + ln_b[lane];
    __syncthreads();
    sh[lane] = ln;
    __syncthreads();
    if (lane < 10) {
        float acc = bc[lane];
        const float* wc = Wc + lane * 64;
#pragma unroll
        for (int j = 0; j < 64; ++j) acc = fmaf(wc[j], sh[j], acc);
        out[b * 10 + lane] = acc;
    }
}

// ---------- backward scan, a-sequence only: one wave per batch ----------
// QUAD-GRAM (exact extension of validated pair-Gram): per 4 steps compute
// 10 INDEPENDENT reductions (D0-3 = u.k_i; 6 within-quad Gram g_ij), then a
// pure-VALU scalar solve, then one parallel u update. Dots use the
// REPLICATED layout: each lane reads a float4 slice (rows of 16 lanes each
// hold the full 64-vector), so a dot = 4 local fmas + 4 DPP row-reduce and
// the result is uniform in every lane's VGPR -- no readlane on the path.
// Staging mechanism identical to R5 (asm loads + VMWAIT(0) + LDS ring).
__global__ __launch_bounds__(64) void scan_a_kernel(
    const float* __restrict__ x, const float* __restrict__ pos_emb,
    const float* __restrict__ W_in, const float* __restrict__ Wq,
    const float* __restrict__ k_ws, float* ab /* alpha in, a out */)
{
    const int lane = threadIdx.x;
    const int b    = blockIdx.x;
    __shared__ __align__(16) float kbuf[2][16][64];   // 8 KB ring
    __shared__ __align__(16) float al_lds[SEQ];       // alpha, preloaded
    __shared__ __align__(16) float a_lds[SEQ];        // a output park
    __shared__ __align__(16) float sh[64];

    const float* kb  = k_ws + (size_t)b * SEQ * 64;
    float*       abp = ab + b * SEQ;

    // preload all alpha into LDS (one-time)
#pragma unroll
    for (int j = 0; j < 13; ++j) {
        const int idx = j * 64 + lane;
        if (idx < SEQ) al_lds[idx] = abp[idx];
    }

    // u init: q at last position (component-per-lane layout)
    {
        const float h = gelu_exact(fmaf(x[b * SEQ + 783], W_in[lane], pos_emb[783 * 64 + lane]));
        sh[lane] = h;
    }
    __syncthreads();
    float u = 0.f;
    {
        const float4* wq4 = (const float4*)(Wq + lane * 64);
        const float4* h4  = (const float4*)sh;
#pragma unroll
        for (int i = 0; i < 16; ++i) {
            float4 hv = h4[i], qv = wq4[i];
            u = fmaf(hv.x, qv.x, u);
            u = fmaf(hv.y, qv.y, u);
            u = fmaf(hv.z, qv.z, u);
            u = fmaf(hv.w, qv.w, u);
        }
    }
    // convert u to replicated float4 layout: lane l holds comps 4*(l%16)..+3
    __syncthreads();
    sh[lane] = u;
    __syncthreads();
    float4 uq = ((const float4*)sh)[lane & 15];

    float kst[16];   // staging regs: live only SLOAD -> next WR

#define SLOAD(c)                                               \
    do {                                                       \
        const int tb_ = 783 - (c) * 16;                        \
        _Pragma("unroll")                                      \
        for (int i = 0; i < 16; ++i)                           \
            kst[i] = gload_f32(&kb[(tb_ - i) * 64 + lane]);    \
    } while (0)

#define WR(bufidx)                                             \
    do {                                                       \
        _Pragma("unroll")                                      \
        for (int i = 0; i < 16; ++i)                           \
            kbuf[bufidx][i][lane] = kst[i];                    \
    } while (0)

#define CMP(bufidx, c)                                                    \
    do {                                                                  \
        const int tb_ = 783 - (c) * 16;                                   \
        _Pragma("unroll")                                                 \
        for (int qq = 0; qq < 4; ++qq) {                                  \
            const int s0_ = 4 * qq;                                       \
            const float4 k0 = ((const float4*)kbuf[bufidx][s0_ + 0])[lane & 15]; \
            const float4 k1 = ((const float4*)kbuf[bufidx][s0_ + 1])[lane & 15]; \
            const float4 k2 = ((const float4*)kbuf[bufidx][s0_ + 2])[lane & 15]; \
            const float4 k3 = ((const float4*)kbuf[bufidx][s0_ + 3])[lane & 15]; \
            const float4 av = *(const float4*)&al_lds[tb_ - s0_ - 3];     \
            const float g01 = row16_allsum(dot4(k0, k1));                 \
            const float g02 = row16_allsum(dot4(k0, k2));                 \
            const float g03 = row16_allsum(dot4(k0, k3));                 \
            const float g12 = row16_allsum(dot4(k1, k2));                 \
            const float g13 = row16_allsum(dot4(k1, k3));                 \
            const float g23 = row16_allsum(dot4(k2, k3));                 \
            const float D0  = row16_allsum(dot4(uq, k0));                 \
            const float D1  = row16_allsum(dot4(uq, k1));                 \
            const float D2  = row16_allsum(dot4(uq, k2));                 \
            const float D3  = row16_allsum(dot4(uq, k3));                 \
            const float a0 = av.w * D0;                                   \
            const float d1 = fmaf(-a0, g01, D1);                          \
            const float a1 = av.z * d1;                                   \
            const float d2 = fmaf(-a1, g12, fmaf(-a0, g02, D2));          \
            const float a2 = av.y * d2;                                   \
            const float d3 = fmaf(-a2, g23, fmaf(-a1, g13, fmaf(-a0, g03, D3))); \
            const float a3 = av.x * d3;                                   \
            uq.x = fmaf(-a3, k3.x, fmaf(-a2, k2.x, fmaf(-a1, k1.x, fmaf(-a0, k0.x, uq.x)))); \
            uq.y = fmaf(-a3, k3.y, fmaf(-a2, k2.y, fmaf(-a1, k1.y, fmaf(-a0, k0.y, uq.y)))); \
            uq.z = fmaf(-a3, k3.z, fmaf(-a2, k2.z, fmaf(-a1, k1.z, fmaf(-a0, k0.z, uq.z)))); \
            uq.w = fmaf(-a3, k3.w, fmaf(-a2, k2.w, fmaf(-a1, k1.w, fmaf(-a0, k0.w, uq.w)))); \
            if (lane == 0) {                                              \
                a_lds[tb_ - s0_ - 0] = a0;                                \
                a_lds[tb_ - s0_ - 1] = a1;                                \
                a_lds[tb_ - s0_ - 2] = a2;                                \
                a_lds[tb_ - s0_ - 3] = a3;                                \
            }                                                             \
        }                                                                 \
    } while (0)

    // Drain all compiler-generated prologue VMEM so counts start at 0.
    VMWAIT(0);
    SLOAD(0);
    VMWAIT(0);
    WR(0);
    SLOAD(1);
#pragma unroll 1
    for (int c = 0; c < 47; ++c) {
        VMWAIT(0);                 // chunk c+1 landed
        WR((c + 1) & 1);
        SLOAD(c + 2);              // in flight across CMP(c)
        CMP(c & 1, c);
    }
    VMWAIT(0);
    WR(0);                         // chunk 48 -> buf 0
    CMP(1, 47);
    CMP(0, 48);
#undef SLOAD
#undef WR
#undef CMP

    // flush a-sequence to global (overwrites alpha_ws in place)
    asm volatile("s_waitcnt lgkmcnt(0)" ::: "memory");
#pragma unroll
    for (int j = 0; j < 13; ++j) {
        const int idx = j * 64 + lane;
        if (idx < SEQ) abp[idx] = a_lds[idx];
    }
}

// ---------- w accumulation + epilogue at higher occupancy ----------
__global__ __launch_bounds__(512) void wsum_kernel(
    const float* __restrict__ x, const float* __restrict__ W_in,
    const float* __restrict__ pos_emb, const float* __restrict__ a_ws,
    const float* __restrict__ Wv, const float* __restrict__ ln_g,
    const float* __restrict__ ln_b, const float* __restrict__ Wc,
    const float* __restrict__ bc, float* __restrict__ out)
{
    const int lane = threadIdx.x & 63;
    const int wv   = threadIdx.x >> 6;        // 0..7
    const int b    = blockIdx.x;
    const float win = W_in[lane];
    const float* ap = a_ws + b * SEQ;
    const float* xp = x + b * SEQ;

    float w = 0.f;
    const int t0 = wv * 98;
#pragma unroll 2
    for (int i = 0; i < 98; ++i) {
        const int t = t0 + i;
        const float h = gelu_exact(fmaf(xp[t], win, pos_emb[t * 64 + lane]));
        w = fmaf(ap[t], h, w);
    }

    __shared__ __align__(16) float swr[8][64];
    __shared__ __align__(16) float sh[64];
    swr[wv][lane] = w;
    __syncthreads();
    if (wv != 0) return;

    w = swr[0][lane] + swr[1][lane] + swr[2][lane] + swr[3][lane]
      + swr[4][lane] + swr[5][lane] + swr[6][lane] + swr[7][lane];
    sh[lane] = w;
    asm volatile("s_waitcnt lgkmcnt(0)" ::: "memory");
    float last = 0.f;
    const float4* wv4 = (const float4*)(Wv + lane * 64);
    const float4* w4  = (const float4*)sh;
#pragma unroll
    for (int i = 0; i < 16; ++i) {
        float4 hv = w4[i], vv = wv4[i];
        last = fmaf(hv.x, vv.x, last);
        last = fmaf(hv.y, vv.y, last);
        last = fmaf(hv.z, vv.z, last);
        last = fmaf(hv.w, vv.w, last);
    }
    const float mu  = wave_allsum(last) * 0.015625f;
    const float dd  = last - mu;
    const float var = wave_allsum(dd * dd) * 0.015625f;
    const float ln  = dd / sqrtf(var + 1e-5f) * ln_g[lane] + ln_b[lane];
    asm volatile("s_waitcnt lgkmcnt(0)" ::: "memory");
    sh[lane] = ln;
    asm volatile("s_waitcnt lgkmcnt(0)" ::: "memory");
    if (lane < 10) {
        float acc = bc[lane];
        const float* wc = Wc + lane * 64;
#pragma unroll
        for (int j = 0; j < 64; ++j) acc = fmaf(wc[j], sh[j], acc);
        out[b * 10 + lane] = acc;
    }
}

// ---------- fused fallback (no workspace needed) ----------
__global__ __launch_bounds__(64) void fused_kernel(
    const float* __restrict__ x, const float* __restrict__ W_in,
    const float* __restrict__ pos_emb, const float* __restrict__ Wq,
    const float* __restrict__ Wk, const float* __restrict__ Wv,
    const float* __restrict__ Wb, const float* __restrict__ bbp,
    const float* __restrict__ ln_g, const float* __restrict__ ln_b,
    const float* __restrict__ Wc, const float* __restrict__ bc,
    float* __restrict__ out)
{
    const int lane = threadIdx.x;
    const int b    = blockIdx.x;
    __shared__ __align__(16) float sh[64];
    const float win = W_in[lane];
    const float wb  = Wb[lane];
    const float bb  = bbp[0];

    float4 wkr[16];
    const float4* wk4 = (const float4*)(Wk + lane * 64);
#pragma unroll
    for (int i = 0; i < 16; ++i) wkr[i] = wk4[i];

    float u;
    {
        const float h = gelu_exact(fmaf(x[b * SEQ + 783], win, pos_emb[783 * 64 + lane]));
        sh[lane] = h;
        __syncthreads();
        u = 0.f;
        const float4* wq4 = (const float4*)(Wq + lane * 64);
        const float4* h4  = (const float4*)sh;
#pragma unroll
        for (int i = 0; i < 16; ++i) {
            float4 hv = h4[i], qv = wq4[i];
            u = fmaf(hv.x, qv.x, u);
            u = fmaf(hv.y, qv.y, u);
            u = fmaf(hv.z, qv.z, u);
            u = fmaf(hv.w, qv.w, u);
        }
    }
    float w = 0.f;
    for (int t = 783; t >= 0; --t) {
        const float h = gelu_exact(fmaf(x[b * SEQ + t], win, pos_emb[t * 64 + lane]));
        const float bdot = wave_allsum(h * wb);
        __syncthreads();
        sh[lane] = h;
        __syncthreads();
        float kd = 0.f;
        const float4* h4 = (const float4*)sh;
#pragma unroll
        for (int i = 0; i < 16; ++i) {
            float4 hv = h4[i];
            kd = fmaf(hv.x, wkr[i].x, kd);
            kd = fmaf(hv.y, wkr[i].y, kd);
            kd = fmaf(hv.z, wkr[i].z, kd);
            kd = fmaf(hv.w, wkr[i].w, kd);
        }
        float lam = wave_allsum(kd * kd);
        lam = fmaxf(lam, 1e-6f);
        const float beta = 1.0f / (1.0f + expf(-(bdot + bb)));
        const float al   = -expm1f(-beta * lam) / (lam + 1e-6f);
        const float dot  = wave_allsum(u * kd);
        const float a    = al * dot;
        u = fmaf(-a, kd, u);
        w = fmaf(a, h, w);
    }
    epilogue(b, lane, w, sh, Wv, ln_g, ln_b, Wc, bc, out);
}

extern "C" void kernel_launch(void* const* d_in, const int* in_sizes, int n_in,
                              void* d_out, int out_size, void* d_ws, size_t ws_size,
                              hipStream_t stream)
{
    const float* x       = (const float*)d_in[0];
    const float* W_in    = (const float*)d_in[1];
    const float* pos_emb = (const float*)d_in[2];
    const float* Wq      = (const float*)d_in[3];
    const float* Wk      = (const float*)d_in[4];
    const float* Wv      = (const float*)d_in[5];
    const float* Wb      = (const float*)d_in[6];
    const float* bb      = (const float*)d_in[7];
    const float* ln_g    = (const float*)d_in[8];
    const float* ln_b    = (const float*)d_in[9];
    const float* Wc      = (const float*)d_in[10];
    const float* bc      = (const float*)d_in[11];
    float* out = (float*)d_out;

    const size_t k_elems = (size_t)BATCH * SEQ * 64;
    const size_t need = k_elems * sizeof(float) + (size_t)BATCH * SEQ * sizeof(float);

    if (ws_size >= need) {
        float* k_ws     = (float*)d_ws;
        float* alpha_ws = k_ws + k_elems;
        prepass_kernel<<<4096, 64, 0, stream>>>(x, W_in, pos_emb, Wk, Wb, bb, k_ws, alpha_ws);
        scan_a_kernel<<<BATCH, 64, 0, stream>>>(x, pos_emb, W_in, Wq, k_ws, alpha_ws);
        wsum_kernel<<<BATCH, 512, 0, stream>>>(x, W_in, pos_emb, alpha_ws, Wv, ln_g, ln_b,
                                               Wc, bc, out);
    } else {
        fused_kernel<<<BATCH, 64, 0, stream>>>(x, W_in, pos_emb, Wq, Wk, Wv, Wb, bb,
                                               ln_g, ln_b, Wc, bc, out);
    }
}

// Round 7
// 166.483 us; speedup vs baseline: 1.0673x; 1.0288x over previous
//
#include <hip/hip_runtime.h>
#include <math.h>

#define DIM 64
#define SEQ 784
#define BATCH 256

// ---------- cross-lane helpers (wave64 reduction via DPP) ----------
template <int CTRL>
__device__ __forceinline__ float dpp_add_step(float s) {
    int v = __builtin_amdgcn_update_dpp(0, __float_as_int(s), CTRL, 0xF, 0xF, false);
    return s + __int_as_float(v);
}

// Sum across all 64 lanes; result broadcast (uniform, via readlane 63).
__device__ __forceinline__ float wave_allsum(float x) {
    x = dpp_add_step<0xB1>(x);   // quad_perm [1,0,3,2]  (xor 1)
    x = dpp_add_step<0x4E>(x);   // quad_perm [2,3,0,1]  (xor 2)
    x = dpp_add_step<0x141>(x);  // row_half_mirror      (pairs across quads)
    x = dpp_add_step<0x140>(x);  // row_mirror           (pairs across 8-groups)
    x = dpp_add_step<0x142>(x);  // row_bcast15          (16 -> 32)
    x = dpp_add_step<0x143>(x);  // row_bcast31          (32 -> 64, lane63 = total)
    return __int_as_float(__builtin_amdgcn_readlane(__float_as_int(x), 63));
}

// 16-lane row allsum: with data replicated 4x across the four rows, every
// lane ends with the FULL sum (uniform) -- 4 DPP steps, NO readlane.
__device__ __forceinline__ float row16_allsum(float x) {
    x = dpp_add_step<0xB1>(x);   // xor 1
    x = dpp_add_step<0x4E>(x);   // xor 2
    x = dpp_add_step<0x141>(x);  // row_half_mirror
    x = dpp_add_step<0x140>(x);  // row_mirror
    return x;
}

__device__ __forceinline__ float dot4(float4 a, float4 b) {
    return fmaf(a.w, b.w, fmaf(a.z, b.z, fmaf(a.y, b.y, a.x * b.x)));
}

__device__ __forceinline__ float gelu_exact(float v) {
    return 0.5f * v * (1.0f + erff(v * 0.70710678118654752440f));
}

#define VMWAIT(N)                                                   \
    do {                                                            \
        asm volatile("s_waitcnt vmcnt(" #N ")" ::: "memory");       \
        __builtin_amdgcn_sched_barrier(0);                          \
    } while (0)

#define LGKMWAIT()                                                  \
    asm volatile("s_waitcnt lgkmcnt(0)" ::: "memory")

// Zero-instruction cross-lane LDS ordering for a single wave.
#define WAVE_FENCE()                                                \
    do {                                                            \
        __builtin_amdgcn_wave_barrier();                            \
        asm volatile("" ::: "memory");                              \
    } while (0)

// global -> LDS DMA, 16B per lane: lds dest = uniform base + lane*16,
// global src is per-lane (gptr + lane*16 passed explicitly).
__device__ __forceinline__ void gload_lds16(const float* gptr, float* lptr) {
    __builtin_amdgcn_global_load_lds(
        (const __attribute__((address_space(1))) void*)gptr,
        (__attribute__((address_space(3))) void*)lptr, 16, 0, 0);
}

// ---------- prepass: k[b,s,:] and alpha[b,s] for all rows ----------
// (64,4): min 4 waves/EU -> 128-VGPR budget, enough for the wkr[16] cache
// (64 VGPRs) that the default budget (VGPR_Count=48 in R6!) was spilling.
__global__ __launch_bounds__(64, 4) void prepass_kernel(
    const float* __restrict__ x, const float* __restrict__ W_in,
    const float* __restrict__ pos_emb, const float* __restrict__ Wk,
    const float* __restrict__ Wb, const float* __restrict__ bbp,
    float* __restrict__ k_ws, float* __restrict__ alpha_ws)
{
    const int lane = threadIdx.x;
    const int gw   = blockIdx.x;              // 0..4095
    const int b    = gw >> 4;                 // /16
    const int s0   = (gw & 15) * 49;

    float4 wkr[16];
    const float4* wk4 = (const float4*)(Wk + lane * 64);
#pragma unroll
    for (int i = 0; i < 16; ++i) wkr[i] = wk4[i];
    const float win = W_in[lane];
    const float wb  = Wb[lane];
    const float bb  = bbp[0];

    const float xv = (lane < 49) ? x[b * SEQ + s0 + lane] : 0.f;

    __shared__ __align__(16) float hbuf[2][64];

    for (int r = 0; r < 49; ++r) {
        const int s = s0 + r;
        const float xs = __shfl(xv, r);
        const float pe = pos_emb[s * 64 + lane];
        const float h  = gelu_exact(fmaf(xs, win, pe));
        const float bdot = wave_allsum(h * wb);
        float* hb = hbuf[r & 1];
        hb[lane] = h;
        WAVE_FENCE();
        const float4* h4 = (const float4*)hb;
        float kd = 0.f;
#pragma unroll
        for (int i = 0; i < 16; ++i) {
            float4 hv = h4[i];
            kd = fmaf(hv.x, wkr[i].x, kd);
            kd = fmaf(hv.y, wkr[i].y, kd);
            kd = fmaf(hv.z, wkr[i].z, kd);
            kd = fmaf(hv.w, wkr[i].w, kd);
        }
        float lam = wave_allsum(kd * kd);
        lam = fmaxf(lam, 1e-6f);
        const float beta = 1.0f / (1.0f + expf(-(bdot + bb)));
        const float al   = -expm1f(-beta * lam) / (lam + 1e-6f);
        const int row = b * SEQ + s;
        k_ws[row * 64 + lane] = kd;
        if (lane == 0) alpha_ws[row] = al;
    }
}

// ---------- shared epilogue (fused fallback only) ----------
__device__ __forceinline__ void epilogue(
    int b, int lane, float w, float* sh,
    const float* __restrict__ Wv, const float* __restrict__ ln_g,
    const float* __restrict__ ln_b, const float* __restrict__ Wc,
    const float* __restrict__ bc, float* __restrict__ out)
{
    __syncthreads();
    sh[lane] = w;
    __syncthreads();
    float last = 0.f;
    const float4* wv4 = (const float4*)(Wv + lane * 64);
    const float4* w4  = (const float4*)sh;
#pragma unroll
    for (int i = 0; i < 16; ++i) {
        float4 hv = w4[i], vv = wv4[i];
        last = fmaf(hv.x, vv.x, last);
        last = fmaf(hv.y, vv.y, last);
        last = fmaf(hv.z, vv.z, last);
        last = fmaf(hv.w, vv.w, last);
    }
    const float mu  = wave_allsum(last) * 0.015625f;
    const float dd  = last - mu;
    const float var = wave_allsum(dd * dd) * 0.015625f;
    const float ln  = dd / sqrtf(var + 1e-5f) * ln_g[lane] + ln_b[lane];
    __syncthreads();
    sh[lane] = ln;
    __syncthreads();
    if (lane < 10) {
        float acc = bc[lane];
        const float* wc = Wc + lane * 64;
#pragma unroll
        for (int j = 0; j < 64; ++j) acc = fmaf(wc[j], sh[j], acc);
        out[b * 10 + lane] = acc;
    }
}

// ---------- backward scan, a-sequence only: one wave per batch ----------
// Quad-Gram CMP identical to R6 (validated absmax 0.0). NEW: (a) launch
// bounds (64,1) -> full 512-VGPR budget so the compiler can batch-issue
// memory ops instead of just-in-time serialization; (b) ZERO VMEM in the
// steady loop: k staged 7 chunks at a time into double-buffered LDS via
// global_load_lds DMA, drained once per group (VMWAIT(0) every ~7x CMP).
__global__ __launch_bounds__(64, 1) void scan_a_kernel(
    const float* __restrict__ x, const float* __restrict__ pos_emb,
    const float* __restrict__ W_in, const float* __restrict__ Wq,
    const float* __restrict__ k_ws, float* ab /* alpha in, a out */)
{
    const int lane = threadIdx.x;
    const int b    = blockIdx.x;
    // 2 x 7 chunks x 16 steps x 64 floats = 57,344 B
    __shared__ __align__(16) float kb_lds[2][7 * 16 * 64];
    __shared__ __align__(16) float al_lds[SEQ];       // alpha, preloaded
    __shared__ __align__(16) float a_lds[SEQ];        // a output park
    __shared__ __align__(16) float sh[64];

    const float* kb  = k_ws + (size_t)b * SEQ * 64;
    float*       abp = ab + b * SEQ;

    // preload all alpha into LDS (one-time)
#pragma unroll
    for (int j = 0; j < 13; ++j) {
        const int idx = j * 64 + lane;
        if (idx < SEQ) al_lds[idx] = abp[idx];
    }

    // u init: q at last position (component-per-lane layout)
    {
        const float h = gelu_exact(fmaf(x[b * SEQ + 783], W_in[lane], pos_emb[783 * 64 + lane]));
        sh[lane] = h;
    }
    __syncthreads();
    float u = 0.f;
    {
        const float4* wq4 = (const float4*)(Wq + lane * 64);
        const float4* h4  = (const float4*)sh;
#pragma unroll
        for (int i = 0; i < 16; ++i) {
            float4 hv = h4[i], qv = wq4[i];
            u = fmaf(hv.x, qv.x, u);
            u = fmaf(hv.y, qv.y, u);
            u = fmaf(hv.z, qv.z, u);
            u = fmaf(hv.w, qv.w, u);
        }
    }
    // convert u to replicated float4 layout: lane l holds comps 4*(l%16)..+3
    __syncthreads();
    sh[lane] = u;
    __syncthreads();
    float4 uq = ((const float4*)sh)[lane & 15];

    // Stage group grp (chunks 7*grp .. 7*grp+6; global rows Tlo..Tlo+111,
    // Tlo = 672-112*grp) into region reg. 28 DMA issues of 16B/lane.
#define STAGE(grp, reg_)                                          \
    do {                                                          \
        const float* gsrc = kb + (672 - 112 * (grp)) * 64 + lane * 4; \
        float* ldst = &kb_lds[reg_][0];                           \
        _Pragma("unroll")                                         \
        for (int m = 0; m < 28; ++m)                              \
            gload_lds16(gsrc + m * 256, ldst + m * 256);          \
    } while (0)

    // lr (LDS row) = t - Tlo; for chunk cc within group, lrb = 111-16*cc,
    // T = absolute t of step 0 of the chunk.
#define CMP(reg_, lrb_, T_)                                               \
    do {                                                                  \
        _Pragma("unroll")                                                 \
        for (int qq = 0; qq < 4; ++qq) {                                  \
            const int s0_ = 4 * qq;                                       \
            const float4 k0 = ((const float4*)&kb_lds[reg_][((lrb_) - s0_    ) * 64])[lane & 15]; \
            const float4 k1 = ((const float4*)&kb_lds[reg_][((lrb_) - s0_ - 1) * 64])[lane & 15]; \
            const float4 k2 = ((const float4*)&kb_lds[reg_][((lrb_) - s0_ - 2) * 64])[lane & 15]; \
            const float4 k3 = ((const float4*)&kb_lds[reg_][((lrb_) - s0_ - 3) * 64])[lane & 15]; \
            const float4 av = *(const float4*)&al_lds[(T_) - s0_ - 3];    \
            const float g01 = row16_allsum(dot4(k0, k1));                 \
            const float g02 = row16_allsum(dot4(k0, k2));                 \
            const float g03 = row16_allsum(dot4(k0, k3));                 \
            const float g12 = row16_allsum(dot4(k1, k2));                 \
            const float g13 = row16_allsum(dot4(k1, k3));                 \
            const float g23 = row16_allsum(dot4(k2, k3));                 \
            const float D0  = row16_allsum(dot4(uq, k0));                 \
            const float D1  = row16_allsum(dot4(uq, k1));                 \
            const float D2  = row16_allsum(dot4(uq, k2));                 \
            const float D3  = row16_allsum(dot4(uq, k3));                 \
            const float a0 = av.w * D0;                                   \
            const float d1 = fmaf(-a0, g01, D1);                          \
            const float a1 = av.z * d1;                                   \
            const float d2 = fmaf(-a1, g12, fmaf(-a0, g02, D2));          \
            const float a2 = av.y * d2;                                   \
            const float d3 = fmaf(-a2, g23, fmaf(-a1, g13, fmaf(-a0, g03, D3))); \
            const float a3 = av.x * d3;                                   \
            uq.x = fmaf(-a3, k3.x, fmaf(-a2, k2.x, fmaf(-a1, k1.x, fmaf(-a0, k0.x, uq.x)))); \
            uq.y = fmaf(-a3, k3.y, fmaf(-a2, k2.y, fmaf(-a1, k1.y, fmaf(-a0, k0.y, uq.y)))); \
            uq.z = fmaf(-a3, k3.z, fmaf(-a2, k2.z, fmaf(-a1, k1.z, fmaf(-a0, k0.z, uq.z)))); \
            uq.w = fmaf(-a3, k3.w, fmaf(-a2, k2.w, fmaf(-a1, k1.w, fmaf(-a0, k0.w, uq.w)))); \
            if (lane == 0) {                                              \
                a_lds[(T_) - s0_ - 0] = a0;                               \
                a_lds[(T_) - s0_ - 1] = a1;                               \
                a_lds[(T_) - s0_ - 2] = a2;                               \
                a_lds[(T_) - s0_ - 3] = a3;                               \
            }                                                             \
        }                                                                 \
    } while (0)

    STAGE(0, 0);
    VMWAIT(0);                 // drain stage 0 + all prologue VMEM
    WAVE_FENCE();
    int reg = 0;
#pragma unroll 1
    for (int g = 0; g < 7; ++g) {
        if (g < 6) {
            LGKMWAIT();        // prior group's ds_reads fully done
            STAGE(g + 1, reg ^ 1);
            __builtin_amdgcn_sched_barrier(0);
        }
#pragma unroll 1
        for (int cc = 0; cc < 7; ++cc) {
            const int T   = 783 - 112 * g - 16 * cc;
            const int lrb = 111 - 16 * cc;
            CMP(reg, lrb, T);
        }
        VMWAIT(0);             // next group's staged data landed in LDS
        WAVE_FENCE();
        reg ^= 1;
    }
#undef STAGE
#undef CMP

    // flush a-sequence to global (overwrites alpha_ws in place)
    LGKMWAIT();
#pragma unroll
    for (int j = 0; j < 13; ++j) {
        const int idx = j * 64 + lane;
        if (idx < SEQ) abp[idx] = a_lds[idx];
    }
}

// ---------- w accumulation + epilogue at higher occupancy ----------
__global__ __launch_bounds__(512) void wsum_kernel(
    const float* __restrict__ x, const float* __restrict__ W_in,
    const float* __restrict__ pos_emb, const float* __restrict__ a_ws,
    const float* __restrict__ Wv, const float* __restrict__ ln_g,
    const float* __restrict__ ln_b, const float* __restrict__ Wc,
    const float* __restrict__ bc, float* __restrict__ out)
{
    const int lane = threadIdx.x & 63;
    const int wv   = threadIdx.x >> 6;        // 0..7
    const int b    = blockIdx.x;
    const float win = W_in[lane];
    const float* ap = a_ws + b * SEQ;
    const float* xp = x + b * SEQ;

    float w = 0.f;
    const int t0 = wv * 98;
#pragma unroll 2
    for (int i = 0; i < 98; ++i) {
        const int t = t0 + i;
        const float h = gelu_exact(fmaf(xp[t], win, pos_emb[t * 64 + lane]));
        w = fmaf(ap[t], h, w);
    }

    __shared__ __align__(16) float swr[8][64];
    __shared__ __align__(16) float sh[64];
    swr[wv][lane] = w;
    __syncthreads();
    if (wv != 0) return;

    w = swr[0][lane] + swr[1][lane] + swr[2][lane] + swr[3][lane]
      + swr[4][lane] + swr[5][lane] + swr[6][lane] + swr[7][lane];
    sh[lane] = w;
    LGKMWAIT();
    float last = 0.f;
    const float4* wv4 = (const float4*)(Wv + lane * 64);
    const float4* w4  = (const float4*)sh;
#pragma unroll
    for (int i = 0; i < 16; ++i) {
        float4 hv = w4[i], vv = wv4[i];
        last = fmaf(hv.x, vv.x, last);
        last = fmaf(hv.y, vv.y, last);
        last = fmaf(hv.z, vv.z, last);
        last = fmaf(hv.w, vv.w, last);
    }
    const float mu  = wave_allsum(last) * 0.015625f;
    const float dd  = last - mu;
    const float var = wave_allsum(dd * dd) * 0.015625f;
    const float ln  = dd / sqrtf(var + 1e-5f) * ln_g[lane] + ln_b[lane];
    LGKMWAIT();
    sh[lane] = ln;
    LGKMWAIT();
    if (lane < 10) {
        float acc = bc[lane];
        const float* wc = Wc + lane * 64;
#pragma unroll
        for (int j = 0; j < 64; ++j) acc = fmaf(wc[j], sh[j], acc);
        out[b * 10 + lane] = acc;
    }
}

// ---------- fused fallback (no workspace needed) ----------
__global__ __launch_bounds__(64) void fused_kernel(
    const float* __restrict__ x, const float* __restrict__ W_in,
    const float* __restrict__ pos_emb, const float* __restrict__ Wq,
    const float* __restrict__ Wk, const float* __restrict__ Wv,
    const float* __restrict__ Wb, const float* __restrict__ bbp,
    const float* __restrict__ ln_g, const float* __restrict__ ln_b,
    const float* __restrict__ Wc, const float* __restrict__ bc,
    float* __restrict__ out)
{
    const int lane = threadIdx.x;
    const int b    = blockIdx.x;
    __shared__ __align__(16) float sh[64];
    const float win = W_in[lane];
    const float wb  = Wb[lane];
    const float bb  = bbp[0];

    float4 wkr[16];
    const float4* wk4 = (const float4*)(Wk + lane * 64);
#pragma unroll
    for (int i = 0; i < 16; ++i) wkr[i] = wk4[i];

    float u;
    {
        const float h = gelu_exact(fmaf(x[b * SEQ + 783], win, pos_emb[783 * 64 + lane]));
        sh[lane] = h;
        __syncthreads();
        u = 0.f;
        const float4* wq4 = (const float4*)(Wq + lane * 64);
        const float4* h4  = (const float4*)sh;
#pragma unroll
        for (int i = 0; i < 16; ++i) {
            float4 hv = h4[i], qv = wq4[i];
            u = fmaf(hv.x, qv.x, u);
            u = fmaf(hv.y, qv.y, u);
            u = fmaf(hv.z, qv.z, u);
            u = fmaf(hv.w, qv.w, u);
        }
    }
    float w = 0.f;
    for (int t = 783; t >= 0; --t) {
        const float h = gelu_exact(fmaf(x[b * SEQ + t], win, pos_emb[t * 64 + lane]));
        const float bdot = wave_allsum(h * wb);
        __syncthreads();
        sh[lane] = h;
        __syncthreads();
        float kd = 0.f;
        const float4* h4 = (const float4*)sh;
#pragma unroll
        for (int i = 0; i < 16; ++i) {
            float4 hv = h4[i];
            kd = fmaf(hv.x, wkr[i].x, kd);
            kd = fmaf(hv.y, wkr[i].y, kd);
            kd = fmaf(hv.z, wkr[i].z, kd);
            kd = fmaf(hv.w, wkr[i].w, kd);
        }
        float lam = wave_allsum(kd * kd);
        lam = fmaxf(lam, 1e-6f);
        const float beta = 1.0f / (1.0f + expf(-(bdot + bb)));
        const float al   = -expm1f(-beta * lam) / (lam + 1e-6f);
        const float dot  = wave_allsum(u * kd);
        const float a    = al * dot;
        u = fmaf(-a, kd, u);
        w = fmaf(a, h, w);
    }
    epilogue(b, lane, w, sh, Wv, ln_g, ln_b, Wc, bc, out);
}

extern "C" void kernel_launch(void* const* d_in, const int* in_sizes, int n_in,
                              void* d_out, int out_size, void* d_ws, size_t ws_size,
                              hipStream_t stream)
{
    const float* x       = (const float*)d_in[0];
    const float* W_in    = (const float*)d_in[1];
    const float* pos_emb = (const float*)d_in[2];
    const float* Wq      = (const float*)d_in[3];
    const float* Wk      = (const float*)d_in[4];
    const float* Wv      = (const float*)d_in[5];
    const float* Wb      = (const float*)d_in[6];
    const float* bb      = (const float*)d_in[7];
    const float* ln_g    = (const float*)d_in[8];
    const float* ln_b    = (const float*)d_in[9];
    const float* Wc      = (const float*)d_in[10];
    const float* bc      = (const float*)d_in[11];
    float* out = (float*)d_out;

    const size_t k_elems = (size_t)BATCH * SEQ * 64;
    const size_t need = k_elems * sizeof(float) + (size_t)BATCH * SEQ * sizeof(float);

    if (ws_size >= need) {
        float* k_ws     = (float*)d_ws;
        float* alpha_ws = k_ws + k_elems;
        prepass_kernel<<<4096, 64, 0, stream>>>(x, W_in, pos_emb, Wk, Wb, bb, k_ws, alpha_ws);
        scan_a_kernel<<<BATCH, 64, 0, stream>>>(x, pos_emb, W_in, Wq, k_ws, alpha_ws);
        wsum_kernel<<<BATCH, 512, 0, stream>>>(x, W_in, pos_emb, alpha_ws, Wv, ln_g, ln_b,
                                               Wc, bc, out);
    } else {
        fused_kernel<<<BATCH, 64, 0, stream>>>(x, W_in, pos_emb, Wq, Wk, Wv, Wb, bb,
                                               ln_g, ln_b, Wc, bc, out);
    }
}

// Round 8
// 126.890 us; speedup vs baseline: 1.4003x; 1.3120x over previous
//
#include <hip/hip_runtime.h>
#include <math.h>

#define DIM 64
#define SEQ 784
#define BATCH 256
// scan decomposition: 7 groups x 112 rows; each group = 7 chunks of 16 steps

// ---------- cross-lane helpers (wave64 reduction via DPP) ----------
template <int CTRL>
__device__ __forceinline__ float dpp_add_step(float s) {
    int v = __builtin_amdgcn_update_dpp(0, __float_as_int(s), CTRL, 0xF, 0xF, false);
    return s + __int_as_float(v);
}

// Sum across all 64 lanes; result broadcast (uniform, via readlane 63).
__device__ __forceinline__ float wave_allsum(float x) {
    x = dpp_add_step<0xB1>(x);   // xor 1
    x = dpp_add_step<0x4E>(x);   // xor 2
    x = dpp_add_step<0x141>(x);  // row_half_mirror
    x = dpp_add_step<0x140>(x);  // row_mirror
    x = dpp_add_step<0x142>(x);  // row_bcast15
    x = dpp_add_step<0x143>(x);  // row_bcast31
    return __int_as_float(__builtin_amdgcn_readlane(__float_as_int(x), 63));
}

// 16-lane row allsum (replicated layout): 4 DPP steps, uniform result, no readlane.
__device__ __forceinline__ float row16_allsum(float x) {
    x = dpp_add_step<0xB1>(x);
    x = dpp_add_step<0x4E>(x);
    x = dpp_add_step<0x141>(x);
    x = dpp_add_step<0x140>(x);
    return x;
}

__device__ __forceinline__ float dot4(float4 a, float4 b) {
    return fmaf(a.w, b.w, fmaf(a.z, b.z, fmaf(a.y, b.y, a.x * b.x)));
}

__device__ __forceinline__ float gelu_exact(float v) {
    return 0.5f * v * (1.0f + erff(v * 0.70710678118654752440f));
}

// Zero-instruction wave-local LDS ordering (compile-time only; same-wave DS
// ops complete in order in HW). Validated in R5-R7 prepass (absmax 0.0).
#define WAVE_FENCE()                                                \
    do {                                                            \
        __builtin_amdgcn_wave_barrier();                            \
        asm volatile("" ::: "memory");                              \
    } while (0)

// ---------- the fully fused kernel: one block (8 waves) per batch ----------
// wave 0: scanner (quad-Gram, byte-identical math to R7, absmax 0.0)
// waves 1-7: producers (prepass of next group into double-buffered LDS)
// then: all 8 waves wsum + wave-0 epilogue. k/alpha/a never touch global.
__global__ __launch_bounds__(512, 2) void fused_all(
    const float* __restrict__ x, const float* __restrict__ W_in,
    const float* __restrict__ pos_emb, const float* __restrict__ Wq,
    const float* __restrict__ Wk, const float* __restrict__ Wv,
    const float* __restrict__ Wb, const float* __restrict__ bbp,
    const float* __restrict__ ln_g, const float* __restrict__ ln_b,
    const float* __restrict__ Wc, const float* __restrict__ bc,
    float* __restrict__ out)
{
    const int lane = threadIdx.x & 63;
    const int wv   = threadIdx.x >> 6;     // 0..7
    const int b    = blockIdx.x;

    __shared__ __align__(16) float kbuf[2][112][64];   // 57,344 B (double buffer)
    __shared__ __align__(16) float al_lds[SEQ];        // alpha (absolute t)
    __shared__ __align__(16) float a_lds[SEQ];         // a output (absolute t)
    __shared__ __align__(16) float hbuf[8][2][64];     // per-wave h ping-pong
    __shared__ __align__(16) float sh[64];             // wave-0 scratch
    __shared__ __align__(16) float swr[8][64];         // wsum block reduce

    const float win = W_in[lane];

    // ---- producer constants (waves 1-7; harmless for wave 0) ----
    float4 wkr[16];
    {
        const float4* wk4 = (const float4*)(Wk + lane * 64);
#pragma unroll
        for (int i = 0; i < 16; ++i) wkr[i] = wk4[i];
    }
    const float wb = Wb[lane];
    const float bb = bbp[0];

    // produce 16 rows of group g into kbuf[buf]: wave wv handles LDS rows
    // (wv-1)*16 .. +15. Row math identical to validated prepass.
    auto produce = [&](int g, int buf) {
        const int base = 672 - 112 * g;
        const int r0   = (wv - 1) * 16;
        float* hb0 = hbuf[wv][0];
        float* hb1 = hbuf[wv][1];
#pragma unroll 1
        for (int i = 0; i < 16; ++i) {
            const int r = r0 + i;
            const int s = base + r;
            const float xs = x[b * SEQ + s];          // wave-uniform scalar
            const float pe = pos_emb[s * 64 + lane];
            const float h  = gelu_exact(fmaf(xs, win, pe));
            const float bdot = wave_allsum(h * wb);
            float* hb = (i & 1) ? hb1 : hb0;
            hb[lane] = h;
            WAVE_FENCE();
            const float4* h4 = (const float4*)hb;
            float kd = 0.f;
#pragma unroll
            for (int j = 0; j < 16; ++j) {
                float4 hv = h4[j];
                kd = fmaf(hv.x, wkr[j].x, kd);
                kd = fmaf(hv.y, wkr[j].y, kd);
                kd = fmaf(hv.z, wkr[j].z, kd);
                kd = fmaf(hv.w, wkr[j].w, kd);
            }
            float lam = wave_allsum(kd * kd);
            lam = fmaxf(lam, 1e-6f);
            const float beta = 1.0f / (1.0f + expf(-(bdot + bb)));
            const float al   = -expm1f(-beta * lam) / (lam + 1e-6f);
            kbuf[buf][r][lane] = kd;
            if (lane == 0) al_lds[s] = al;
        }
    };

    // ---- phase 0: u-init (wave 0) overlapped with produce(group 0) ----
    float4 uq = make_float4(0.f, 0.f, 0.f, 0.f);
    if (wv == 0) {
        const float h = gelu_exact(fmaf(x[b * SEQ + 783], win, pos_emb[783 * 64 + lane]));
        sh[lane] = h;
        WAVE_FENCE();
        float u = 0.f;
        const float4* wq4 = (const float4*)(Wq + lane * 64);
        const float4* h4  = (const float4*)sh;
#pragma unroll
        for (int i = 0; i < 16; ++i) {
            float4 hv = h4[i], qv = wq4[i];
            u = fmaf(hv.x, qv.x, u);
            u = fmaf(hv.y, qv.y, u);
            u = fmaf(hv.z, qv.z, u);
            u = fmaf(hv.w, qv.w, u);
        }
        WAVE_FENCE();                  // all reads of sh(h) done (in-order DS)
        sh[lane] = u;
        WAVE_FENCE();
        uq = ((const float4*)sh)[lane & 15];   // replicated float4 layout
    } else {
        produce(0, 0);
    }
    __syncthreads();

    // quad-Gram CMP: byte-identical math to R7 (validated absmax 0.0).
#define CMP(reg_, lrb_, T_)                                               \
    do {                                                                  \
        _Pragma("unroll")                                                 \
        for (int qq = 0; qq < 4; ++qq) {                                  \
            const int s0_ = 4 * qq;                                       \
            const float4 k0 = ((const float4*)kbuf[reg_][(lrb_) - s0_    ])[lane & 15]; \
            const float4 k1 = ((const float4*)kbuf[reg_][(lrb_) - s0_ - 1])[lane & 15]; \
            const float4 k2 = ((const float4*)kbuf[reg_][(lrb_) - s0_ - 2])[lane & 15]; \
            const float4 k3 = ((const float4*)kbuf[reg_][(lrb_) - s0_ - 3])[lane & 15]; \
            const float4 av = *(const float4*)&al_lds[(T_) - s0_ - 3];    \
            const float g01 = row16_allsum(dot4(k0, k1));                 \
            const float g02 = row16_allsum(dot4(k0, k2));                 \
            const float g03 = row16_allsum(dot4(k0, k3));                 \
            const float g12 = row16_allsum(dot4(k1, k2));                 \
            const float g13 = row16_allsum(dot4(k1, k3));                 \
            const float g23 = row16_allsum(dot4(k2, k3));                 \
            const float D0  = row16_allsum(dot4(uq, k0));                 \
            const float D1  = row16_allsum(dot4(uq, k1));                 \
            const float D2  = row16_allsum(dot4(uq, k2));                 \
            const float D3  = row16_allsum(dot4(uq, k3));                 \
            const float a0 = av.w * D0;                                   \
            const float d1 = fmaf(-a0, g01, D1);                          \
            const float a1 = av.z * d1;                                   \
            const float d2 = fmaf(-a1, g12, fmaf(-a0, g02, D2));          \
            const float a2 = av.y * d2;                                   \
            const float d3 = fmaf(-a2, g23, fmaf(-a1, g13, fmaf(-a0, g03, D3))); \
            const float a3 = av.x * d3;                                   \
            uq.x = fmaf(-a3, k3.x, fmaf(-a2, k2.x, fmaf(-a1, k1.x, fmaf(-a0, k0.x, uq.x)))); \
            uq.y = fmaf(-a3, k3.y, fmaf(-a2, k2.y, fmaf(-a1, k1.y, fmaf(-a0, k0.y, uq.y)))); \
            uq.z = fmaf(-a3, k3.z, fmaf(-a2, k2.z, fmaf(-a1, k1.z, fmaf(-a0, k0.z, uq.z)))); \
            uq.w = fmaf(-a3, k3.w, fmaf(-a2, k2.w, fmaf(-a1, k1.w, fmaf(-a0, k0.w, uq.w)))); \
            if (lane == 0) {                                              \
                a_lds[(T_) - s0_ - 0] = a0;                               \
                a_lds[(T_) - s0_ - 1] = a1;                               \
                a_lds[(T_) - s0_ - 2] = a2;                               \
                a_lds[(T_) - s0_ - 3] = a3;                               \
            }                                                             \
        }                                                                 \
    } while (0)

    // ---- main loop: wave 0 scans group g; waves 1-7 produce group g+1 ----
#pragma unroll 1
    for (int g = 0; g < 7; ++g) {
        if (wv == 0) {
            const int reg = g & 1;
#pragma unroll 1
            for (int cc = 0; cc < 7; ++cc) {
                const int T   = 783 - 112 * g - 16 * cc;
                const int lrb = 111 - 16 * cc;
                CMP(reg, lrb, T);
            }
        } else if (g < 6) {
            produce(g + 1, (g + 1) & 1);
        }
        __syncthreads();
    }
#undef CMP

    // ---- wsum: all 8 waves, 98 rows each ----
    float w = 0.f;
    {
        const int t0 = wv * 98;
#pragma unroll 2
        for (int i = 0; i < 98; ++i) {
            const int t = t0 + i;
            const float h = gelu_exact(fmaf(x[b * SEQ + t], win, pos_emb[t * 64 + lane]));
            w = fmaf(a_lds[t], h, w);
        }
    }
    swr[wv][lane] = w;
    __syncthreads();
    if (wv != 0) return;

    // ---- wave-0 epilogue: last = Wv*w -> LN -> logits (validated math) ----
    w = swr[0][lane] + swr[1][lane] + swr[2][lane] + swr[3][lane]
      + swr[4][lane] + swr[5][lane] + swr[6][lane] + swr[7][lane];
    sh[lane] = w;
    WAVE_FENCE();
    float last = 0.f;
    const float4* wv4 = (const float4*)(Wv + lane * 64);
    const float4* w4  = (const float4*)sh;
#pragma unroll
    for (int i = 0; i < 16; ++i) {
        float4 hv = w4[i], vv = wv4[i];
        last = fmaf(hv.x, vv.x, last);
        last = fmaf(hv.y, vv.y, last);
        last = fmaf(hv.z, vv.z, last);
        last = fmaf(hv.w, vv.w, last);
    }
    const float mu  = wave_allsum(last) * 0.015625f;
    const float dd  = last - mu;
    const float var = wave_allsum(dd * dd) * 0.015625f;
    const float ln  = dd / sqrtf(var + 1e-5f) * ln_g[lane] + ln_b[lane];
    WAVE_FENCE();
    sh[lane] = ln;
    WAVE_FENCE();
    if (lane < 10) {
        float acc = bc[lane];
        const float* wc = Wc + lane * 64;
#pragma unroll
        for (int j = 0; j < 64; ++j) acc = fmaf(wc[j], sh[j], acc);
        out[b * 10 + lane] = acc;
    }
}

extern "C" void kernel_launch(void* const* d_in, const int* in_sizes, int n_in,
                              void* d_out, int out_size, void* d_ws, size_t ws_size,
                              hipStream_t stream)
{
    const float* x       = (const float*)d_in[0];
    const float* W_in    = (const float*)d_in[1];
    const float* pos_emb = (const float*)d_in[2];
    const float* Wq      = (const float*)d_in[3];
    const float* Wk      = (const float*)d_in[4];
    const float* Wv      = (const float*)d_in[5];
    const float* Wb      = (const float*)d_in[6];
    const float* bb      = (const float*)d_in[7];
    const float* ln_g    = (const float*)d_in[8];
    const float* ln_b    = (const float*)d_in[9];
    const float* Wc      = (const float*)d_in[10];
    const float* bc      = (const float*)d_in[11];
    float* out = (float*)d_out;

    // fully fused: no workspace needed at all
    fused_all<<<BATCH, 512, 0, stream>>>(x, W_in, pos_emb, Wq, Wk, Wv, Wb, bb,
                                         ln_g, ln_b, Wc, bc, out);
}